// Round 4
// baseline (242.523 us; speedup 1.0000x reference)
//
#include <hip/hip_runtime.h>

// CRF sequence labeling: B=64, S=512, H=1024, L=9
// R4: two kernels.
//   K12 fused_kernel : grid = B*NCHUNK = 1024 blocks x 256 (4 blocks/CU @39KB LDS).
//     Phase A: block computes its chunk's 32x9 emissions (GEMM vs LDS-staged W)
//              straight into LDS — feats never hits global memory.
//     Phase B: wave0 = chunk gold-score/mask partials; waves1-2 = the 9
//              independent 9-lane log2-semiring row recursions (chunk transfer
//              matrix P_c); wave3 (chunk 0) exports alpha0 row.
//     Recursion tails overlap other blocks' HBM-bound GEMM loads.
//   K3 final_kernel  : per batch: alpha0 ⊗ P_0 ⊗ ... ⊗ P_15 + gold partials sum;
//     atomicAdd of (norm-score)*ln2/B into d_out (zeroed by K12 block 0).
// All LSE math in base-2 domain (scores pre-scaled by log2 e).

#define BATCH 64
#define SEQ   512
#define HID   1024
#define NLAB  9
#define CHUNK 32
#define NCHUNK (SEQ / CHUNK)   // 16

__device__ __forceinline__ float exp2_fast(float x) { return __builtin_amdgcn_exp2f(x); }
__device__ __forceinline__ float log2_fast(float x) { return __builtin_amdgcn_logf(x); }

#define LOG2E 1.4426950408889634f
#define LN2   0.6931471805599453f

__global__ __launch_bounds__(256) void fused_kernel(
    const float* __restrict__ inp, const float* __restrict__ Wg,
    const float* __restrict__ bias, const float* __restrict__ trans,
    const int* __restrict__ labels, const int* __restrict__ mask,
    float* __restrict__ P, float* __restrict__ a0buf,
    float* __restrict__ goldpart, float* __restrict__ msumpart,
    float* __restrict__ out)
{
    __shared__ float Wl[NLAB * 1056];       // 1024 + 32 skew pad per label row
    __shared__ float em[CHUNK][NLAB];       // chunk emissions (already *LOG2E)
    const int tid = threadIdx.x;
    if (blockIdx.x == 0 && tid == 255) out[0] = 0.0f;   // init for K3 atomics

    const int b = blockIdx.x >> 4;
    const int c = blockIdx.x & (NCHUNK - 1);
    const int t0 = c * CHUNK;

    for (int i = tid; i < NLAB * HID; i += 256) {
        int l = i >> 10, col = i & 1023;
        Wl[l * 1056 + col + (col >> 5)] = Wg[i];
    }
    __syncthreads();

    // ---- Phase A: emissions for this chunk's 32 rows ----
    // 16 groups of 16 lanes; group gg handles rows 2gg, 2gg+1 of the chunk.
    const int lane = tid & 63;
    const int wv   = tid >> 6;
    const int p    = lane & 15;
    const int gg   = wv * 4 + (lane >> 4);
    const float* r = inp + ((long)b * SEQ + t0 + 2 * gg) * HID;

    float acc[2][NLAB];
    #pragma unroll
    for (int rr = 0; rr < 2; ++rr)
        #pragma unroll
        for (int l = 0; l < NLAB; ++l) acc[rr][l] = 0.f;

    #pragma unroll
    for (int c4 = 0; c4 < 4; ++c4) {
        const int col0 = c4 * 256 + p * 16;
        const int sk = col0 + (col0 >> 5);
        float xs[2][16];
        #pragma unroll
        for (int rr = 0; rr < 2; ++rr) {
            const float* rp = r + (long)rr * HID + col0;
            #pragma unroll
            for (int q = 0; q < 4; ++q)
                ((float4*)xs[rr])[q] = ((const float4*)rp)[q];
        }
        #pragma unroll
        for (int l = 0; l < NLAB; ++l) {
            const float* wp = &Wl[l * 1056 + sk];
            float w[16];
            #pragma unroll
            for (int q = 0; q < 4; ++q)
                ((float4*)w)[q] = ((const float4*)wp)[q];
            #pragma unroll
            for (int rr = 0; rr < 2; ++rr) {
                float a = acc[rr][l];
                #pragma unroll
                for (int k = 0; k < 16; ++k) a = fmaf(xs[rr][k], w[k], a);
                acc[rr][l] = a;
            }
        }
    }
    #pragma unroll
    for (int rr = 0; rr < 2; ++rr)
        #pragma unroll
        for (int l = 0; l < NLAB; ++l) {
            float a = acc[rr][l];
            a += __shfl_xor(a, 8, 64);
            a += __shfl_xor(a, 4, 64);
            a += __shfl_xor(a, 2, 64);
            a += __shfl_xor(a, 1, 64);
            acc[rr][l] = a;
        }
    if (p == 0) {
        #pragma unroll
        for (int rr = 0; rr < 2; ++rr)
            #pragma unroll
            for (int l = 0; l < NLAB; ++l)
                em[2 * gg + rr][l] = (acc[rr][l] + bias[l]) * LOG2E;
    }
    __syncthreads();

    // ---- Phase B ----
    const int* mb = mask + b * SEQ;
    const int* lb = labels + b * SEQ;

    if (wv == 0) {
        // gold-score + mask-count partials for this chunk (lanes 0..31)
        float gp = 0.f, ms = 0.f;
        if (lane < CHUNK) {
            int t = t0 + lane;
            int mt = mb[t];
            if (mt > 0) {
                int tag = lb[t];
                gp = em[lane][tag];
                ms = 1.f;
                if (t > 0) gp += trans[lb[t - 1] * NLAB + tag] * LOG2E;
            }
        }
        #pragma unroll
        for (int off = 32; off > 0; off >>= 1) {
            gp += __shfl_xor(gp, off, 64);
            ms += __shfl_xor(ms, off, 64);
        }
        if (lane == 0) {
            goldpart[b * NCHUNK + c] = gp;
            msumpart[b * NCHUNK + c] = ms;
        }
    } else if (wv <= 2) {
        // 9 independent row recursions: wave1 rows 0..6, wave2 rows 7..8.
        const int g9 = lane / 9;
        const int j  = lane - g9 * 9;
        const bool act = (wv == 1) ? (g9 < 7) : (g9 < 2);
        const int i = (wv == 1) ? g9 : 7 + g9;
        const int sbase = g9 * 9;

        float tr[NLAB];
        #pragma unroll
        for (int k = 0; k < NLAB; ++k) tr[k] = trans[k * NLAB + j] * LOG2E;
        const int isafe = act ? i : 0;
        const float tri = trans[isafe * NLAB + j] * LOG2E;

        const int ts = (c == 0) ? 1 : t0;
        const int te = t0 + CHUNK;

        float a;
        {
            int m0 = mb[ts];
            float e0 = em[ts - t0][j];
            float aid = (isafe == j) ? 0.0f : -1e30f;
            a = (m0 > 0) ? (tri + e0) : aid;
        }
        int m_nxt = mb[ts + 1];
        for (int t = ts + 1; t < te; ++t) {
            int mt = m_nxt;
            if (t + 1 < te) m_nxt = mb[t + 1];
            float e = em[t - t0][j];
            float v[NLAB];
            #pragma unroll
            for (int k = 0; k < NLAB; ++k) v[k] = __shfl(a, sbase + k, 64) + tr[k];
            float m01 = fmaxf(v[0], v[1]), m23 = fmaxf(v[2], v[3]);
            float m45 = fmaxf(v[4], v[5]), m67 = fmaxf(v[6], v[7]);
            float mx = fmaxf(fmaxf(fmaxf(m01, m23), fmaxf(m45, m67)), v[8]);
            float s = 0.0f;
            #pragma unroll
            for (int k = 0; k < NLAB; ++k) s += exp2_fast(v[k] - mx);
            float an = mx + log2_fast(s) + e;
            a = (mt > 0) ? an : a;
        }
        if (act) P[(long)((b * NCHUNK + c) * NLAB + i) * NLAB + j] = a;
    } else {
        // wave3: chunk-0 block exports alpha0 emission row (feats[b,0,:])
        if (c == 0 && lane < NLAB) a0buf[b * NLAB + lane] = em[0][lane];
    }
}

// ---------------------------------------------------------------------------
// K3: per-batch finalize. Grid: 64 blocks x 64.
// ---------------------------------------------------------------------------
__global__ __launch_bounds__(64) void final_kernel(
    const float* __restrict__ startv, const float* __restrict__ endv,
    const int* __restrict__ labels, const float* __restrict__ P,
    const float* __restrict__ a0buf, const float* __restrict__ goldpart,
    const float* __restrict__ msumpart, float* __restrict__ out)
{
    const int b = blockIdx.x, lane = threadIdx.x;

    // gold score = sum of chunk partials
    float gp = (lane < NCHUNK) ? goldpart[b * NCHUNK + lane] : 0.f;
    float ms = (lane < NCHUNK) ? msumpart[b * NCHUNK + lane] : 0.f;
    #pragma unroll
    for (int off = 32; off > 0; off >>= 1) {
        gp += __shfl_xor(gp, off, 64);
        ms += __shfl_xor(ms, off, 64);
    }

    // alpha chain over chunk matrices
    const int j = lane % 9;
    float al = a0buf[b * NLAB + j] + startv[j] * LOG2E;
    const float* Pb = P + (long)b * NCHUNK * 81;
    float pc[NLAB];
    #pragma unroll
    for (int i = 0; i < NLAB; ++i) pc[i] = Pb[i * NLAB + j];
    #pragma unroll
    for (int c = 0; c < NCHUNK; ++c) {
        float pn[NLAB];
        if (c < NCHUNK - 1) {
            #pragma unroll
            for (int i = 0; i < NLAB; ++i) pn[i] = Pb[(c + 1) * 81 + i * NLAB + j];
        } else {
            #pragma unroll
            for (int i = 0; i < NLAB; ++i) pn[i] = 0.0f;
        }
        float v[NLAB];
        #pragma unroll
        for (int i = 0; i < NLAB; ++i) v[i] = __shfl(al, i, 64) + pc[i];
        float m01 = fmaxf(v[0], v[1]), m23 = fmaxf(v[2], v[3]);
        float m45 = fmaxf(v[4], v[5]), m67 = fmaxf(v[6], v[7]);
        float mx = fmaxf(fmaxf(fmaxf(m01, m23), fmaxf(m45, m67)), v[8]);
        float s = 0.0f;
        #pragma unroll
        for (int i = 0; i < NLAB; ++i) s += exp2_fast(v[i] - mx);
        al = mx + log2_fast(s);
        #pragma unroll
        for (int i = 0; i < NLAB; ++i) pc[i] = pn[i];
    }
    al += endv[j] * LOG2E;

    float v[NLAB];
    #pragma unroll
    for (int i = 0; i < NLAB; ++i) v[i] = __shfl(al, i, 64);
    float m01 = fmaxf(v[0], v[1]), m23 = fmaxf(v[2], v[3]);
    float m45 = fmaxf(v[4], v[5]), m67 = fmaxf(v[6], v[7]);
    float mx = fmaxf(fmaxf(fmaxf(m01, m23), fmaxf(m45, m67)), v[8]);
    float s = 0.0f;
    #pragma unroll
    for (int i = 0; i < NLAB; ++i) s += exp2_fast(v[i] - mx);
    float norm = mx + log2_fast(s);

    if (lane == 0) {
        const int* lb = labels + b * SEQ;
        int msum = (int)ms;
        int li = (msum > 0) ? (msum - 1) : 0;
        float score = gp + startv[lb[0]] * LOG2E + endv[lb[li]] * LOG2E;
        atomicAdd(out, (norm - score) * (LN2 / (float)BATCH));
    }
}

extern "C" void kernel_launch(void* const* d_in, const int* in_sizes, int n_in,
                              void* d_out, int out_size, void* d_ws, size_t ws_size,
                              hipStream_t stream)
{
    const float* inp    = (const float*)d_in[0];
    const int*   labels = (const int*)d_in[1];
    const int*   mask   = (const int*)d_in[2];
    const float* W      = (const float*)d_in[3];
    const float* bias   = (const float*)d_in[4];
    const float* trans  = (const float*)d_in[5];
    const float* startv = (const float*)d_in[6];
    const float* endv   = (const float*)d_in[7];

    float* P        = (float*)d_ws;                       // B*NCHUNK*81 floats
    float* a0buf    = P + BATCH * NCHUNK * 81;            // B*9
    float* goldpart = a0buf + BATCH * NLAB;               // B*16
    float* msumpart = goldpart + BATCH * NCHUNK;          // B*16
    float* out      = (float*)d_out;

    hipLaunchKernelGGL(fused_kernel, dim3(BATCH * NCHUNK), dim3(256), 0, stream,
                       inp, W, bias, trans, labels, mask,
                       P, a0buf, goldpart, msumpart, out);
    hipLaunchKernelGGL(final_kernel, dim3(BATCH), dim3(64), 0, stream,
                       startv, endv, labels, P, a0buf, goldpart, msumpart, out);
}

// Round 5
// 237.573 us; speedup vs baseline: 1.0208x; 1.0208x over previous
//
#include <hip/hip_runtime.h>
#include <hip/hip_bf16.h>

// CRF sequence labeling: B=64, S=512, H=1024, L=9
// R5: MFMA logits + R3-style recursion kernels.
//   K0 wcvt_kernel   : W[9,1024] -> wbf[16,1024] bf16, pre-scaled by log2(e),
//                      rows 9..15 zero (N-pad for 16-wide MFMA tiles).
//   K1 logits_kernel : feats = inputs @ W^T via mfma_f32_16x16x32_bf16.
//                      No LDS, no cross-lane reduction: MFMA does the K-reduce.
//                      Wave = 2 independent 16-row M-tiles, K-loop of 32 steps.
//   K2 chunk_kernel  : per (b, chunk of 32, row i): 9x9 log2-semiring chunk
//                      transfer-matrix row recursion (R3 form, best measured).
//   K3 final_kernel  : per batch alpha chain + gold score; atomicAdd mean.
// All LSE math in base-2 domain (W and scores pre-scaled by log2 e).

#define BATCH 64
#define SEQ   512
#define HID   1024
#define NLAB  9
#define CHUNK 32
#define NCHUNK (SEQ / CHUNK)          // 16
#define NREC (BATCH * NCHUNK * NLAB)  // 9216
#define NROWS (BATCH * SEQ)           // 32768
#define NTILES (NROWS / 16)           // 2048 M-tiles

__device__ __forceinline__ float exp2_fast(float x) { return __builtin_amdgcn_exp2f(x); }
__device__ __forceinline__ float log2_fast(float x) { return __builtin_amdgcn_logf(x); }

#define LOG2E 1.4426950408889634f
#define LN2   0.6931471805599453f

typedef __attribute__((ext_vector_type(8))) short short8;   // 8 bf16 (4 VGPRs)
typedef __attribute__((ext_vector_type(4))) float float4v;  // MFMA C/D

// ---------------------------------------------------------------------------
// K0: W -> bf16, *LOG2E, zero-pad to 16 label rows. 64 blocks x 256.
// ---------------------------------------------------------------------------
__global__ __launch_bounds__(256) void wcvt_kernel(
    const float* __restrict__ W, __hip_bfloat16* __restrict__ wbf)
{
    int idx = blockIdx.x * 256 + threadIdx.x;   // 0..16383
    int n = idx >> 10, k = idx & 1023;
    float v = (n < NLAB) ? W[n * HID + k] * LOG2E : 0.0f;
    wbf[idx] = __float2bfloat16(v);
}

// ---------------------------------------------------------------------------
// K1: MFMA logits. Grid: 256 blocks x 256 = 1024 waves; wave w computes
// M-tiles 2w, 2w+1 (16 rows each). Fragment layouts (m89/m91-verified):
//   A[m=lane&15][k=(lane>>4)*8+j]  -> 32 B contiguous fp32 per lane, cvt bf16
//   B[k=(lane>>4)*8+j][n=lane&15]  -> wbf[n][k..k+8] = 16 B per lane (L1-hot)
//   C: col=lane&15, row=(lane>>4)*4+reg
// No LDS, no shuffles. Per k-step: 5 loads + 8 cvt_pk-ish + 2 MFMA.
// ---------------------------------------------------------------------------
__global__ __launch_bounds__(256) void logits_kernel(
    const float* __restrict__ inp, const __hip_bfloat16* __restrict__ wbf,
    const float* __restrict__ bias, float* __restrict__ feats)
{
    const int lane = threadIdx.x & 63;
    const int wv   = threadIdx.x >> 6;
    const int wid  = blockIdx.x * 4 + wv;        // 0..1023
    const int n    = lane & 15;
    const int q8   = lane >> 4;                  // 0..3
    const long r0  = (long)wid * 32;             // tile0: r0..r0+15, tile1: +16

    const float* a0p = inp + (r0 + n) * HID + q8 * 8;
    const float* a1p = a0p + 16 * HID;
    const short* bp  = (const short*)wbf + n * HID + q8 * 8;

    float4v acc0 = {0.f, 0.f, 0.f, 0.f};
    float4v acc1 = {0.f, 0.f, 0.f, 0.f};

    for (int kk = 0; kk < 32; ++kk) {
        const int ko = kk * 32;
        float x0[8], x1[8];
        *(float4*)(x0)     = *(const float4*)(a0p + ko);
        *(float4*)(x0 + 4) = *(const float4*)(a0p + ko + 4);
        *(float4*)(x1)     = *(const float4*)(a1p + ko);
        *(float4*)(x1 + 4) = *(const float4*)(a1p + ko + 4);
        short8 bfrag = *(const short8*)(bp + ko);

        short8 af0, af1;
        #pragma unroll
        for (int j = 0; j < 8; ++j) {
            union { __hip_bfloat16 h; short s; } u0, u1;
            u0.h = __float2bfloat16(x0[j]);
            u1.h = __float2bfloat16(x1[j]);
            af0[j] = u0.s;
            af1[j] = u1.s;
        }
        acc0 = __builtin_amdgcn_mfma_f32_16x16x32_bf16(af0, bfrag, acc0, 0, 0, 0);
        acc1 = __builtin_amdgcn_mfma_f32_16x16x32_bf16(af1, bfrag, acc1, 0, 0, 0);
    }

    if (n < NLAB) {
        const float bK = bias[n] * LOG2E;
        #pragma unroll
        for (int r = 0; r < 4; ++r) {
            const long row = r0 + q8 * 4 + r;    // C layout: row=(lane>>4)*4+reg
            feats[row * NLAB + n]        = acc0[r] + bK;
            feats[(row + 16) * NLAB + n] = acc1[r] + bK;
        }
    }
}

// ---------------------------------------------------------------------------
// K2: chunk transfer-matrix rows (R3 form). Each 9-lane group runs one row
// recursion; 7 groups/wave; 1317 blocks x 64. Block 0 lane 63 zeroes d_out.
// ---------------------------------------------------------------------------
__global__ __launch_bounds__(64) void chunk_kernel(
    const float* __restrict__ feats, const float* __restrict__ trans,
    const int* __restrict__ mask, float* __restrict__ P,
    float* __restrict__ out)
{
    const int lane = threadIdx.x;
    if (blockIdx.x == 0 && lane == 63) out[0] = 0.0f;   // init for K3 atomics
    const int g = lane / 9;
    const int j = lane - g * 9;
    int rid = blockIdx.x * 7 + g;
    bool act = (g < 7) && (rid < NREC);
    if (!act) rid = 0;

    const int i  = rid % NLAB;
    const int bc = rid / NLAB;
    const int c  = bc & (NCHUNK - 1);
    const int b  = bc >> 4;

    float tr[NLAB];
    #pragma unroll
    for (int k = 0; k < NLAB; ++k) tr[k] = trans[k * NLAB + j] * LOG2E;
    const float tri = trans[i * NLAB + j] * LOG2E;

    const float* fb = feats + (long)b * SEQ * NLAB;
    const int* mb = mask + b * SEQ;
    const int ts = (c == 0) ? 1 : c * CHUNK;
    const int te = (c + 1) * CHUNK;
    const int sbase = g * 9;

    float a;
    {
        int m0 = mb[ts];
        float e0 = fb[ts * NLAB + j];
        float aid = (i == j) ? 0.0f : -1e30f;
        a = (m0 > 0) ? (tri + e0) : aid;
    }

    float e_nxt = fb[(ts + 1) * NLAB + j];
    int   m_nxt = mb[ts + 1];
    for (int t = ts + 1; t < te; ++t) {
        float e = e_nxt;
        int  mt = m_nxt;
        if (t + 1 < te) {               // prefetch next step's emission/mask
            e_nxt = fb[(t + 1) * NLAB + j];
            m_nxt = mb[t + 1];
        }
        float v[NLAB];
        #pragma unroll
        for (int k = 0; k < NLAB; ++k) v[k] = __shfl(a, sbase + k, 64) + tr[k];
        float m01 = fmaxf(v[0], v[1]), m23 = fmaxf(v[2], v[3]);
        float m45 = fmaxf(v[4], v[5]), m67 = fmaxf(v[6], v[7]);
        float mx = fmaxf(fmaxf(fmaxf(m01, m23), fmaxf(m45, m67)), v[8]);
        float s = 0.0f;
        #pragma unroll
        for (int k = 0; k < NLAB; ++k) s += exp2_fast(v[k] - mx);
        float an = mx + log2_fast(s) + e;
        a = (mt > 0) ? an : a;
    }
    if (act) P[(long)rid * NLAB + j] = a;
}

// ---------------------------------------------------------------------------
// K3: per-batch finalize (R3 form + fused mean). Grid: 64 blocks x 64.
// ---------------------------------------------------------------------------
__global__ __launch_bounds__(64) void final_kernel(
    const float* __restrict__ feats, const float* __restrict__ trans,
    const float* __restrict__ startv, const float* __restrict__ endv,
    const int* __restrict__ labels, const int* __restrict__ mask,
    const float* __restrict__ P, float* __restrict__ out)
{
    const int b = blockIdx.x, lane = threadIdx.x;
    const float* fb = feats + (long)b * SEQ * NLAB;
    const int* lb = labels + b * SEQ;
    const int* mb = mask + b * SEQ;

    // ---- gold score ----
    float gsum = 0.0f; int msum = 0;
    for (int t = lane; t < SEQ; t += 64) {
        int tag = lb[t];
        int mt = mb[t];
        if (mt > 0) {
            gsum += fb[t * NLAB + tag];
            msum++;
            if (t > 0) gsum += trans[lb[t - 1] * NLAB + tag] * LOG2E;
        }
    }
    #pragma unroll
    for (int off = 32; off > 0; off >>= 1) {
        gsum += __shfl_xor(gsum, off, 64);
        msum += __shfl_xor(msum, off, 64);
    }

    // ---- alpha chain over chunk matrices ----
    const int j = lane % 9;
    float al = fb[j] + startv[j] * LOG2E;
    const float* Pb = P + (long)b * NCHUNK * 81;
    float pc[NLAB];
    #pragma unroll
    for (int i = 0; i < NLAB; ++i) pc[i] = Pb[i * NLAB + j];
    #pragma unroll
    for (int c = 0; c < NCHUNK; ++c) {
        float pn[NLAB];
        if (c < NCHUNK - 1) {
            #pragma unroll
            for (int i = 0; i < NLAB; ++i) pn[i] = Pb[(c + 1) * 81 + i * NLAB + j];
        } else {
            #pragma unroll
            for (int i = 0; i < NLAB; ++i) pn[i] = 0.0f;
        }
        float v[NLAB];
        #pragma unroll
        for (int i = 0; i < NLAB; ++i) v[i] = __shfl(al, i, 64) + pc[i];
        float m01 = fmaxf(v[0], v[1]), m23 = fmaxf(v[2], v[3]);
        float m45 = fmaxf(v[4], v[5]), m67 = fmaxf(v[6], v[7]);
        float mx = fmaxf(fmaxf(fmaxf(m01, m23), fmaxf(m45, m67)), v[8]);
        float s = 0.0f;
        #pragma unroll
        for (int i = 0; i < NLAB; ++i) s += exp2_fast(v[i] - mx);
        al = mx + log2_fast(s);
        #pragma unroll
        for (int i = 0; i < NLAB; ++i) pc[i] = pn[i];
    }
    al += endv[j] * LOG2E;

    float v[NLAB];
    #pragma unroll
    for (int i = 0; i < NLAB; ++i) v[i] = __shfl(al, i, 64);
    float m01 = fmaxf(v[0], v[1]), m23 = fmaxf(v[2], v[3]);
    float m45 = fmaxf(v[4], v[5]), m67 = fmaxf(v[6], v[7]);
    float mx = fmaxf(fmaxf(fmaxf(m01, m23), fmaxf(m45, m67)), v[8]);
    float s = 0.0f;
    #pragma unroll
    for (int i = 0; i < NLAB; ++i) s += exp2_fast(v[i] - mx);
    float norm = mx + log2_fast(s);

    if (lane == 0) {
        int li = (msum > 0) ? (msum - 1) : 0;
        float score = gsum + startv[lb[0]] * LOG2E + endv[lb[li]] * LOG2E;
        atomicAdd(out, (norm - score) * (LN2 / (float)BATCH));
    }
}

extern "C" void kernel_launch(void* const* d_in, const int* in_sizes, int n_in,
                              void* d_out, int out_size, void* d_ws, size_t ws_size,
                              hipStream_t stream)
{
    const float* inp    = (const float*)d_in[0];
    const int*   labels = (const int*)d_in[1];
    const int*   mask   = (const int*)d_in[2];
    const float* W      = (const float*)d_in[3];
    const float* bias   = (const float*)d_in[4];
    const float* trans  = (const float*)d_in[5];
    const float* startv = (const float*)d_in[6];
    const float* endv   = (const float*)d_in[7];

    float* feats = (float*)d_ws;                         // 294912 floats
    float* P     = feats + (long)NROWS * NLAB;           // 82944 floats
    __hip_bfloat16* wbf = (__hip_bfloat16*)(P + (long)BATCH * NCHUNK * 81); // 16384
    float* out   = (float*)d_out;

    hipLaunchKernelGGL(wcvt_kernel, dim3(64), dim3(256), 0, stream, W, wbf);
    hipLaunchKernelGGL(logits_kernel, dim3(NTILES / 8), dim3(256), 0, stream,
                       inp, wbf, bias, feats);
    hipLaunchKernelGGL(chunk_kernel, dim3((NREC + 6) / 7), dim3(64), 0, stream,
                       feats, trans, mask, P, out);
    hipLaunchKernelGGL(final_kernel, dim3(BATCH), dim3(64), 0, stream,
                       feats, trans, startv, endv, labels, mask, P, out);
}